// Round 1
// baseline (299.188 us; speedup 1.0000x reference)
//
#include <hip/hip_runtime.h>
#include <stdint.h>

typedef __attribute__((ext_vector_type(8))) __bf16 bf16x8;
typedef __attribute__((ext_vector_type(4))) float f32x4;
typedef __attribute__((ext_vector_type(8))) unsigned short u16x8;

__device__ __forceinline__ unsigned short f2bf(float f) {
  union { float f; unsigned u; } v; v.f = f;
  return (unsigned short)((v.u + 0x7FFFu + ((v.u >> 16) & 1u)) >> 16);
}

__device__ __forceinline__ void gload16(const void* g, void* l) {
  __builtin_amdgcn_global_load_lds(
      (const __attribute__((address_space(1))) void*)g,
      (__attribute__((address_space(3))) void*)l, 16, 0, 0);
}

// ---------------------------------------------------------------------------
// pack x: fp32 (8,4096,768) -> bf16 [32768][768] with window permutation
// row m = win*64 + tok ; win = b*64 + wh*8 + ww ; tok = r*8 + c
// source row = b*4096 + (wh*8+r)*64 + (ww*8+c)
// ---------------------------------------------------------------------------
__global__ __launch_bounds__(256) void pack_x_kernel(const float* __restrict__ x,
                                                     unsigned short* __restrict__ xw) {
  int idx = blockIdx.x * 256 + threadIdx.x;   // < 32768*96
  int m = idx / 96;
  int p = idx - m * 96;
  int win = m >> 6, tok = m & 63;
  int b = win >> 6, wh = (win >> 3) & 7, ww = win & 7;
  int r = tok >> 3, c = tok & 7;
  size_t xoff = ((size_t)b * 4096 + (wh * 8 + r) * 64 + (ww * 8 + c)) * 768 + p * 8;
  const float* src = x + xoff;
  u16x8 o;
#pragma unroll
  for (int j = 0; j < 8; ++j) o[j] = f2bf(src[j]);
  *(u16x8*)(xw + (size_t)m * 768 + p * 8) = o;
}

// pack weights: qkv_w (2304x768) and proj_w (768x768) fp32 -> bf16
__global__ __launch_bounds__(256) void pack_w_kernel(const float* __restrict__ qkvw,
                                                     const float* __restrict__ projw,
                                                     unsigned short* __restrict__ wq,
                                                     unsigned short* __restrict__ wp) {
  int idx = blockIdx.x * 256 + threadIdx.x;   // < 294912
  const float* src;
  unsigned short* dst;
  if (idx < 221184) { src = qkvw + (size_t)idx * 8; dst = wq + (size_t)idx * 8; }
  else { int i2 = idx - 221184; src = projw + (size_t)i2 * 8; dst = wp + (size_t)i2 * 8; }
  u16x8 o;
#pragma unroll
  for (int j = 0; j < 8; ++j) o[j] = f2bf(src[j]);
  *(u16x8*)dst = o;
}

// ---------------------------------------------------------------------------
// GEMM1: C[32768][2304] (bf16) = A[32768][768] * B[2304][768]^T + bias
// m97 structure: 128x128 tile, BK=32, 4 waves (2x2), 4x4 16x16x32 frags/wave
// ---------------------------------------------------------------------------
__global__ __launch_bounds__(256) void gemm_qkv_kernel(
    const unsigned short* __restrict__ A, const unsigned short* __restrict__ B,
    const float* __restrict__ bias, unsigned short* __restrict__ C) {
  constexpr int K = 768;
  constexpr int N = 2304;
  __shared__ unsigned short sA[128 * 32];
  __shared__ unsigned short sB[128 * 32];
  const int tid = threadIdx.x;
  const int wave = tid >> 6;
  const int lane = tid & 63;
  const int tm = (blockIdx.x / (N / 128)) * 128;
  const int tn = (blockIdx.x % (N / 128)) * 128;

  // staging: chunk e = tid (+256); row = e>>2, k-offset = (e&3)*8 elems
  const int sr = tid >> 2;
  const int skb = (tid & 3) * 8;
  const unsigned short* gA = A + (size_t)(tm + sr) * K + skb;
  const unsigned short* gB = B + (size_t)(tn + sr) * K + skb;
  char* lA = (char*)sA + wave * 1024;
  char* lB = (char*)sB + wave * 1024;

  const int wr = (wave >> 1) * 64;
  const int wc = (wave & 1) * 64;
  const int lrow = lane & 15;
  const int lkb = (lane >> 4) * 8;

  f32x4 acc[4][4] = {};

  for (int k0 = 0; k0 < K; k0 += 32) {
    __syncthreads();
    gload16(gA + k0, lA);
    gload16(gA + k0 + (size_t)64 * K, lA + 4096);
    gload16(gB + k0, lB);
    gload16(gB + k0 + (size_t)64 * K, lB + 4096);
    __syncthreads();
    bf16x8 af[4], bfv[4];
#pragma unroll
    for (int mi = 0; mi < 4; ++mi)
      af[mi] = *(const bf16x8*)&sA[(wr + mi * 16 + lrow) * 32 + lkb];
#pragma unroll
    for (int ni = 0; ni < 4; ++ni)
      bfv[ni] = *(const bf16x8*)&sB[(wc + ni * 16 + lrow) * 32 + lkb];
#pragma unroll
    for (int mi = 0; mi < 4; ++mi)
#pragma unroll
      for (int ni = 0; ni < 4; ++ni)
        acc[mi][ni] = __builtin_amdgcn_mfma_f32_16x16x32_bf16(af[mi], bfv[ni], acc[mi][ni], 0, 0, 0);
  }

  // C/D layout: col = lane&15, row = (lane>>4)*4 + r   [m89-verified]
  const int crow = tm + wr + ((lane >> 4) << 2);
  const int ccol = tn + wc + lrow;
#pragma unroll
  for (int ni = 0; ni < 4; ++ni) {
    const int col = ccol + ni * 16;
    const float bv = bias[col];
#pragma unroll
    for (int mi = 0; mi < 4; ++mi)
#pragma unroll
      for (int r = 0; r < 4; ++r)
        C[(size_t)(crow + mi * 16 + r) * N + col] = f2bf(acc[mi][ni][r] + bv);
  }
}

// ---------------------------------------------------------------------------
// Attention: one wave per (window, head). qkv rows = win*64+tok, stride 2304.
// q cols [h*64, +64), k cols [768+h*64), v cols [1536+h*64).
// ---------------------------------------------------------------------------
__global__ __launch_bounds__(64) void attn_kernel(const unsigned short* __restrict__ qkv,
                                                  unsigned short* __restrict__ attnout) {
  __shared__ unsigned short sQ[64 * 64];
  __shared__ unsigned short sK[64 * 64];   // reused for P after QK^T
  __shared__ unsigned short sVT[64 * 64];  // V transposed: [d][token]
  const int lane = threadIdx.x;
  const int win = blockIdx.x / 12;
  const int head = blockIdx.x - win * 12;
  const size_t row0 = (size_t)win * 64;
  const int qoff = head * 64, koff = 768 + head * 64, voff = 1536 + head * 64;

#pragma unroll
  for (int i = 0; i < 8; ++i) {
    int e = lane + i * 64;
    int row = e >> 3, cb = (e & 7) * 8;
    gload16(qkv + (row0 + row) * 2304 + qoff + cb, (char*)sQ + i * 1024);
    gload16(qkv + (row0 + row) * 2304 + koff + cb, (char*)sK + i * 1024);
  }
  {  // reg-transpose V: lane owns token=lane, scatters to sVT[d][lane]
    const unsigned short* gv = qkv + (row0 + lane) * 2304 + voff;
#pragma unroll
    for (int j = 0; j < 8; ++j) {
      u16x8 v = *(const u16x8*)(gv + j * 8);
#pragma unroll
      for (int d = 0; d < 8; ++d) sVT[(j * 8 + d) * 64 + lane] = v[d];
    }
  }
  __syncthreads();

  const int lrow = lane & 15;
  const int lkb = (lane >> 4) * 8;

  // S = Q K^T (64x64, K=64)
  f32x4 s[4][4] = {};
#pragma unroll
  for (int ks = 0; ks < 2; ++ks) {
    bf16x8 qf[4], kf[4];
#pragma unroll
    for (int mi = 0; mi < 4; ++mi) qf[mi] = *(const bf16x8*)&sQ[(mi * 16 + lrow) * 64 + ks * 32 + lkb];
#pragma unroll
    for (int ni = 0; ni < 4; ++ni) kf[ni] = *(const bf16x8*)&sK[(ni * 16 + lrow) * 64 + ks * 32 + lkb];
#pragma unroll
    for (int mi = 0; mi < 4; ++mi)
#pragma unroll
      for (int ni = 0; ni < 4; ++ni)
        s[mi][ni] = __builtin_amdgcn_mfma_f32_16x16x32_bf16(qf[mi], kf[ni], s[mi][ni], 0, 0, 0);
  }

  // softmax per row; row's 64 cols live in 4 ni-frags x 16 lanes (same lane>>4 group)
  float p[4][4][4];
#pragma unroll
  for (int mi = 0; mi < 4; ++mi) {
#pragma unroll
    for (int r = 0; r < 4; ++r) {
      float v0 = s[mi][0][r] * 0.125f, v1 = s[mi][1][r] * 0.125f;
      float v2 = s[mi][2][r] * 0.125f, v3 = s[mi][3][r] * 0.125f;
      float mx = fmaxf(fmaxf(v0, v1), fmaxf(v2, v3));
      mx = fmaxf(mx, __shfl_xor(mx, 1));
      mx = fmaxf(mx, __shfl_xor(mx, 2));
      mx = fmaxf(mx, __shfl_xor(mx, 4));
      mx = fmaxf(mx, __shfl_xor(mx, 8));
      float e0 = __expf(v0 - mx), e1 = __expf(v1 - mx);
      float e2 = __expf(v2 - mx), e3 = __expf(v3 - mx);
      float sm = e0 + e1 + e2 + e3;
      sm += __shfl_xor(sm, 1);
      sm += __shfl_xor(sm, 2);
      sm += __shfl_xor(sm, 4);
      sm += __shfl_xor(sm, 8);
      float inv = 1.0f / sm;
      p[mi][0][r] = e0 * inv; p[mi][1][r] = e1 * inv;
      p[mi][2][r] = e2 * inv; p[mi][3][r] = e3 * inv;
    }
  }

  __syncthreads();  // all K-frag reads done before overwriting sK with P
#pragma unroll
  for (int mi = 0; mi < 4; ++mi)
#pragma unroll
    for (int ni = 0; ni < 4; ++ni)
#pragma unroll
      for (int r = 0; r < 4; ++r)
        sK[(mi * 16 + (lane >> 4) * 4 + r) * 64 + ni * 16 + lrow] = f2bf(p[mi][ni][r]);
  __syncthreads();

  // O = P V : A = P (row-major in sK), B = V via sVT[d][n] (k-contig)
  f32x4 o[4][4] = {};
#pragma unroll
  for (int ks = 0; ks < 2; ++ks) {
    bf16x8 pf[4], vf[4];
#pragma unroll
    for (int mi = 0; mi < 4; ++mi) pf[mi] = *(const bf16x8*)&sK[(mi * 16 + lrow) * 64 + ks * 32 + lkb];
#pragma unroll
    for (int ni = 0; ni < 4; ++ni) vf[ni] = *(const bf16x8*)&sVT[(ni * 16 + lrow) * 64 + ks * 32 + lkb];
#pragma unroll
    for (int mi = 0; mi < 4; ++mi)
#pragma unroll
      for (int ni = 0; ni < 4; ++ni)
        o[mi][ni] = __builtin_amdgcn_mfma_f32_16x16x32_bf16(pf[mi], vf[ni], o[mi][ni], 0, 0, 0);
  }

#pragma unroll
  for (int mi = 0; mi < 4; ++mi)
#pragma unroll
    for (int ni = 0; ni < 4; ++ni) {
      int col = head * 64 + ni * 16 + lrow;
#pragma unroll
      for (int r = 0; r < 4; ++r) {
        int trow = mi * 16 + (lane >> 4) * 4 + r;
        attnout[(row0 + trow) * 768 + col] = f2bf(o[mi][ni][r]);
      }
    }
}

// ---------------------------------------------------------------------------
// GEMM2: out(fp32, window-unpermuted) = attnout[32768][768] * proj_w^T + bias
// ---------------------------------------------------------------------------
__global__ __launch_bounds__(256) void gemm_proj_kernel(
    const unsigned short* __restrict__ A, const unsigned short* __restrict__ B,
    const float* __restrict__ bias, float* __restrict__ out) {
  constexpr int K = 768;
  constexpr int N = 768;
  __shared__ unsigned short sA[128 * 32];
  __shared__ unsigned short sB[128 * 32];
  const int tid = threadIdx.x;
  const int wave = tid >> 6;
  const int lane = tid & 63;
  const int tm = (blockIdx.x / (N / 128)) * 128;
  const int tn = (blockIdx.x % (N / 128)) * 128;

  const int sr = tid >> 2;
  const int skb = (tid & 3) * 8;
  const unsigned short* gA = A + (size_t)(tm + sr) * K + skb;
  const unsigned short* gB = B + (size_t)(tn + sr) * K + skb;
  char* lA = (char*)sA + wave * 1024;
  char* lB = (char*)sB + wave * 1024;

  const int wr = (wave >> 1) * 64;
  const int wc = (wave & 1) * 64;
  const int lrow = lane & 15;
  const int lkb = (lane >> 4) * 8;

  f32x4 acc[4][4] = {};

  for (int k0 = 0; k0 < K; k0 += 32) {
    __syncthreads();
    gload16(gA + k0, lA);
    gload16(gA + k0 + (size_t)64 * K, lA + 4096);
    gload16(gB + k0, lB);
    gload16(gB + k0 + (size_t)64 * K, lB + 4096);
    __syncthreads();
    bf16x8 af[4], bfv[4];
#pragma unroll
    for (int mi = 0; mi < 4; ++mi)
      af[mi] = *(const bf16x8*)&sA[(wr + mi * 16 + lrow) * 32 + lkb];
#pragma unroll
    for (int ni = 0; ni < 4; ++ni)
      bfv[ni] = *(const bf16x8*)&sB[(wc + ni * 16 + lrow) * 32 + lkb];
#pragma unroll
    for (int mi = 0; mi < 4; ++mi)
#pragma unroll
      for (int ni = 0; ni < 4; ++ni)
        acc[mi][ni] = __builtin_amdgcn_mfma_f32_16x16x32_bf16(af[mi], bfv[ni], acc[mi][ni], 0, 0, 0);
  }

  const int crow = tm + wr + ((lane >> 4) << 2);
  const int ccol = tn + wc + lrow;
#pragma unroll
  for (int mi = 0; mi < 4; ++mi)
#pragma unroll
    for (int r = 0; r < 4; ++r) {
      int m = crow + mi * 16 + r;
      int win = m >> 6, tok = m & 63;
      int b = win >> 6, wh = (win >> 3) & 7, ww = win & 7;
      int rr = tok >> 3, cc = tok & 7;
      float* op = out + ((size_t)b * 4096 + (wh * 8 + rr) * 64 + (ww * 8 + cc)) * 768;
#pragma unroll
      for (int ni = 0; ni < 4; ++ni) {
        int col = ccol + ni * 16;
        op[col] = acc[mi][ni][r] + bias[col];
      }
    }
}

extern "C" void kernel_launch(void* const* d_in, const int* in_sizes, int n_in,
                              void* d_out, int out_size, void* d_ws, size_t ws_size,
                              hipStream_t stream) {
  (void)in_sizes; (void)n_in; (void)out_size; (void)ws_size;
  const float* x = (const float*)d_in[0];
  const float* qkv_w = (const float*)d_in[1];
  const float* qkv_b = (const float*)d_in[2];
  const float* proj_w = (const float*)d_in[3];
  const float* proj_b = (const float*)d_in[4];
  float* out = (float*)d_out;

  char* ws = (char*)d_ws;
  unsigned short* xw   = (unsigned short*)(ws);                          // 32768*768 bf16 (50.3MB), later reused as attnout
  unsigned short* qkvB = (unsigned short*)(ws + 50331648);               // 32768*2304 bf16 (151MB)
  unsigned short* wq   = (unsigned short*)(ws + 50331648 + 150994944);   // 2304*768 bf16
  unsigned short* wp   = (unsigned short*)(ws + 50331648 + 150994944 + 3538944);  // 768*768 bf16

  pack_x_kernel<<<12288, 256, 0, stream>>>(x, xw);
  pack_w_kernel<<<1152, 256, 0, stream>>>(qkv_w, proj_w, wq, wp);
  gemm_qkv_kernel<<<4608, 256, 0, stream>>>(xw, wq, qkv_b, qkvB);
  attn_kernel<<<6144, 64, 0, stream>>>(qkvB, xw);  // xw reused as attnout (stream-ordered)
  gemm_proj_kernel<<<1536, 256, 0, stream>>>(xw, wp, proj_b, out);
}